// Round 1
// baseline (5329.700 us; speedup 1.0000x reference)
//
#include <hip/hip_runtime.h>

// ---------------------------------------------------------------------------
// GNN traffic predictor: embed -> GCNConv x2 -> edge MLP
// N=100000 nodes, E=1600000 edges, F_NODE=32, F_EDGE=8, H=64
// Strategy round 1: fp32 everywhere; outer-product GEMMs with wave-uniform
// scalar row loads; atomics for scatter; runtime int32/int64 index detection.
// ---------------------------------------------------------------------------

// ---- index dtype detection: flag=1 -> buffer holds int32, 0 -> int64 -------
__global__ void detect_idx_k(const unsigned int* __restrict__ ei, int* __restrict__ flag) {
    int nz = 0;
    for (int i = threadIdx.x; i < 2048; i += 64) {
        // if data is int64 (values < 2^31, nonneg), every odd 32-bit word is 0
        if (ei[2 * i + 1] != 0u) nz = 1;
    }
    unsigned long long m = __ballot(nz);
    if (threadIdx.x == 0) *flag = (m != 0ull) ? 1 : 0;
}

__global__ void cvt_idx_k(const void* __restrict__ ei, const int* __restrict__ flag,
                          int* __restrict__ out, int n) {
    int i = blockIdx.x * 256 + threadIdx.x;
    if (i >= n) return;
    if (*flag) out[i] = ((const int*)ei)[i];
    else       out[i] = (int)((const long long*)ei)[i];
}

// ---- degree / symmetric norm ----------------------------------------------
__global__ void dinv_init_k(float* __restrict__ dinv, int n) {
    int i = blockIdx.x * 256 + threadIdx.x;
    if (i < n) dinv[i] = 1.0f;  // self-loop contributes 1 to degree
}

__global__ void deg_count_k(const int* __restrict__ dst, float* __restrict__ dinv, int E) {
    int i = blockIdx.x * 256 + threadIdx.x;
    if (i < E) unsafeAtomicAdd(&dinv[dst[i]], 1.0f);
}

__global__ void dinv_fin_k(float* __restrict__ dinv, int n) {
    int i = blockIdx.x * 256 + threadIdx.x;
    if (i < n) dinv[i] = rsqrtf(dinv[i]);  // deg >= 1 always
}

// ---- dense layer: o[n,64] = (RELU?)(h[n,K] @ W[K,64] (+b));
//      optional cinit[n,64] = o * dinv[n]^2 (self-loop term, pre-bias) -------
template <int K, bool RELU, bool BIAS, bool CINIT>
__global__ __launch_bounds__(256) void lin_k(
    const float* __restrict__ h, const float* __restrict__ W,
    const float* __restrict__ b, const float* __restrict__ dinv,
    float* __restrict__ o, float* __restrict__ cinit, int n) {
    constexpr int KP = K + 4;              // pad: KP*4 bytes keeps 16B align, breaks bank stride
    __shared__ float Wt[64 * KP];          // transposed: Wt[j][k] = W[k][j]
    int t = threadIdx.x;
    for (int i = t; i < K * 64; i += 256) {
        int k = i >> 6, j = i & 63;
        Wt[j * KP + k] = W[i];
    }
    __syncthreads();
    int lane = t & 63;
    int wave = __builtin_amdgcn_readfirstlane(t) >> 6;  // force SGPR (wave-uniform)
    float bj = BIAS ? b[lane] : 0.0f;
    int node0 = blockIdx.x * 64 + wave * 16;
    for (int g = 0; g < 16; g += 8) {
        int nb = node0 + g;
        float z[8];
#pragma unroll
        for (int tt = 0; tt < 8; tt++) z[tt] = bj;
#pragma unroll
        for (int kc = 0; kc < K; kc += 4) {
            float4 w = *(const float4*)&Wt[lane * KP + kc];
#pragma unroll
            for (int tt = 0; tt < 8; tt++) {
                int nn = nb + tt; nn = nn < n ? nn : n - 1;  // clamp (uniform scalar)
                float4 a = *(const float4*)&h[nn * K + kc];  // wave-uniform address
                z[tt] = fmaf(a.x, w.x, z[tt]);
                z[tt] = fmaf(a.y, w.y, z[tt]);
                z[tt] = fmaf(a.z, w.z, z[tt]);
                z[tt] = fmaf(a.w, w.w, z[tt]);
            }
        }
#pragma unroll
        for (int tt = 0; tt < 8; tt++) {
            int nn = nb + tt;
            if (nn < n) {
                float v = z[tt];
                if (RELU) v = fmaxf(v, 0.0f);
                o[nn * 64 + lane] = v;
                if (CINIT) {
                    float dv = dinv[nn];
                    cinit[nn * 64 + lane] = v * dv * dv;
                }
            }
        }
    }
}

// ---- edge scatter: C[dst] += hW[src] * dinv[src]*dinv[dst] -----------------
__global__ __launch_bounds__(256) void scat_edges_k(
    const float4* __restrict__ hW, const float* __restrict__ dinv,
    const int* __restrict__ src, const int* __restrict__ dst,
    float* __restrict__ C, int E) {
    int i = blockIdx.x * 256 + threadIdx.x;  // edge*16 + quad
    if (i >= E * 16) return;
    int e = i >> 4, q = i & 15;
    int s = src[e], d = dst[e];
    float nrm = dinv[s] * dinv[d];
    float4 v = hW[s * 16 + q];
    float* cp = C + d * 64 + q * 4;
    unsafeAtomicAdd(cp + 0, v.x * nrm);
    unsafeAtomicAdd(cp + 1, v.y * nrm);
    unsafeAtomicAdd(cp + 2, v.z * nrm);
    unsafeAtomicAdd(cp + 3, v.w * nrm);
}

// ---- in-place bias + relu --------------------------------------------------
__global__ void bias_relu_k(float4* __restrict__ C, const float4* __restrict__ b4, int n) {
    int i = blockIdx.x * 256 + threadIdx.x;
    if (i >= n * 16) return;
    int q = i & 15;
    float4 v = C[i], b = b4[q];
    v.x = fmaxf(v.x + b.x, 0.f);
    v.y = fmaxf(v.y + b.y, 0.f);
    v.z = fmaxf(v.z + b.z, 0.f);
    v.w = fmaxf(v.w + b.w, 0.f);
    C[i] = v;
}

// ---- edge MLP: out[e] = relu([h[s],h[d],attr[e]] @ W1 + b1) @ W2 + b2 ------
#define EPB 1024  // edges per block (4 waves x 32 groups of 8)
__global__ __launch_bounds__(256) void edge_mlp_k(
    const float* __restrict__ h, const float* __restrict__ attr,
    const int* __restrict__ src, const int* __restrict__ dst,
    const float* __restrict__ W1, const float* __restrict__ b1,
    const float* __restrict__ W2, const float* __restrict__ b2,
    float* __restrict__ out, int E) {
    constexpr int KP = 140;                // 136 padded; 140*4B is 16B-aligned, bank-spread
    __shared__ float Wt[64 * KP];          // Wt[j][k] = W1[k][j]
    int t = threadIdx.x;
    for (int i = t; i < 136 * 64; i += 256) {
        int k = i >> 6, j = i & 63;
        Wt[j * KP + k] = W1[i];
    }
    __syncthreads();
    int lane = t & 63;
    int wave = __builtin_amdgcn_readfirstlane(t) >> 6;
    float b1j = b1[lane];
    float w2j = W2[lane];
    float b2v = b2[0];
    int e0 = blockIdx.x * EPB + wave * (EPB / 4);
    for (int g = 0; g < EPB / 4; g += 8) {
        int base = e0 + g;
        int ss[8], dd[8], ee[8];
#pragma unroll
        for (int tt = 0; tt < 8; tt++) {
            int e = base + tt; if (e >= E) e = E - 1;
            ee[tt] = e;
            ss[tt] = __builtin_amdgcn_readfirstlane(src[e]);
            dd[tt] = __builtin_amdgcn_readfirstlane(dst[e]);
        }
        float z[8];
#pragma unroll
        for (int tt = 0; tt < 8; tt++) z[tt] = b1j;
        // k in [0,64): h[src]
#pragma unroll
        for (int kc = 0; kc < 64; kc += 4) {
            float4 w = *(const float4*)&Wt[lane * KP + kc];
#pragma unroll
            for (int tt = 0; tt < 8; tt++) {
                float4 a = *(const float4*)&h[ss[tt] * 64 + kc];
                z[tt] = fmaf(a.x, w.x, z[tt]);
                z[tt] = fmaf(a.y, w.y, z[tt]);
                z[tt] = fmaf(a.z, w.z, z[tt]);
                z[tt] = fmaf(a.w, w.w, z[tt]);
            }
        }
        // k in [64,128): h[dst]
#pragma unroll
        for (int kc = 0; kc < 64; kc += 4) {
            float4 w = *(const float4*)&Wt[lane * KP + 64 + kc];
#pragma unroll
            for (int tt = 0; tt < 8; tt++) {
                float4 a = *(const float4*)&h[dd[tt] * 64 + kc];
                z[tt] = fmaf(a.x, w.x, z[tt]);
                z[tt] = fmaf(a.y, w.y, z[tt]);
                z[tt] = fmaf(a.z, w.z, z[tt]);
                z[tt] = fmaf(a.w, w.w, z[tt]);
            }
        }
        // k in [128,136): edge_attr
#pragma unroll
        for (int kc = 0; kc < 8; kc += 4) {
            float4 w = *(const float4*)&Wt[lane * KP + 128 + kc];
#pragma unroll
            for (int tt = 0; tt < 8; tt++) {
                float4 a = *(const float4*)&attr[ee[tt] * 8 + kc];
                z[tt] = fmaf(a.x, w.x, z[tt]);
                z[tt] = fmaf(a.y, w.y, z[tt]);
                z[tt] = fmaf(a.z, w.z, z[tt]);
                z[tt] = fmaf(a.w, w.w, z[tt]);
            }
        }
        // layer 2: relu(z) . W2 + b2, reduce across 64 lanes
#pragma unroll
        for (int tt = 0; tt < 8; tt++) {
            float v = fmaxf(z[tt], 0.f) * w2j;
#pragma unroll
            for (int off = 32; off; off >>= 1) v += __shfl_down(v, off);
            if (lane == 0) {
                int e = base + tt;
                if (e < E) out[e] = v + b2v;
            }
        }
    }
}

extern "C" void kernel_launch(void* const* d_in, const int* in_sizes, int n_in,
                              void* d_out, int out_size, void* d_ws, size_t ws_size,
                              hipStream_t stream) {
    const float* x    = (const float*)d_in[0];
    const float* attr = (const float*)d_in[1];
    const float* W_e  = (const float*)d_in[2];
    const float* b_e  = (const float*)d_in[3];
    const float* W_c1 = (const float*)d_in[4];
    const float* b_c1 = (const float*)d_in[5];
    const float* W_c2 = (const float*)d_in[6];
    const float* b_c2 = (const float*)d_in[7];
    const float* W_p1 = (const float*)d_in[8];
    const float* b_p1 = (const float*)d_in[9];
    const float* W_p2 = (const float*)d_in[10];
    const float* b_p2 = (const float*)d_in[11];
    const void*  ei   = d_in[12];
    int N = in_sizes[0] / 32;
    int E = in_sizes[1] / 8;
    float* out = (float*)d_out;

    // workspace layout (~90 MB)
    char* ws = (char*)d_ws;
    size_t nh = (size_t)N * 64 * 4;
    float* A    = (float*)ws; ws += nh;
    float* B    = (float*)ws; ws += nh;
    float* C    = (float*)ws; ws += nh;
    float* dinv = (float*)ws; ws += (size_t)((N + 3) & ~3) * 4;
    int*   idx  = (int*)ws;   ws += (size_t)2 * E * 4;
    int*   flag = (int*)ws;
    int* srcI = idx;
    int* dstI = idx + E;

    auto cdiv = [](long long a, long long b) { return (int)((a + b - 1) / b); };

    detect_idx_k<<<1, 64, 0, stream>>>((const unsigned int*)ei, flag);
    cvt_idx_k<<<cdiv(2LL * E, 256), 256, 0, stream>>>(ei, flag, idx, 2 * E);
    dinv_init_k<<<cdiv(N, 256), 256, 0, stream>>>(dinv, N);
    deg_count_k<<<cdiv(E, 256), 256, 0, stream>>>(dstI, dinv, E);
    dinv_fin_k<<<cdiv(N, 256), 256, 0, stream>>>(dinv, N);

    int linGrid = cdiv(N, 64);
    // h0 = relu(x @ W_e + b_e) -> A
    lin_k<32, true, true, false><<<linGrid, 256, 0, stream>>>(x, W_e, b_e, nullptr, A, nullptr, N);
    // conv1: hW -> B, C init with self-loop term
    lin_k<64, false, false, true><<<linGrid, 256, 0, stream>>>(A, W_c1, nullptr, dinv, B, C, N);
    scat_edges_k<<<cdiv((long long)E * 16, 256), 256, 0, stream>>>((const float4*)B, dinv, srcI, dstI, C, E);
    bias_relu_k<<<cdiv((long long)N * 16, 256), 256, 0, stream>>>((float4*)C, (const float4*)b_c1, N);
    // conv2: hW -> A, B init with self-loop term
    lin_k<64, false, false, true><<<linGrid, 256, 0, stream>>>(C, W_c2, nullptr, dinv, A, B, N);
    scat_edges_k<<<cdiv((long long)E * 16, 256), 256, 0, stream>>>((const float4*)A, dinv, srcI, dstI, B, E);
    bias_relu_k<<<cdiv((long long)N * 16, 256), 256, 0, stream>>>((float4*)B, (const float4*)b_c2, N);
    // edge MLP -> out
    edge_mlp_k<<<cdiv(E, EPB), 256, 0, stream>>>(B, attr, srcI, dstI, W_p1, b_p1, W_p2, b_p2, out, E);
}

// Round 2
// 1470.900 us; speedup vs baseline: 3.6234x; 3.6234x over previous
//
#include <hip/hip_runtime.h>

// ---------------------------------------------------------------------------
// GNN traffic predictor: embed -> GCNConv x2 -> edge MLP
// N=100000, E=1600000, F_NODE=32, F_EDGE=8, H=64
// Round 2: register-tiled fp32 GEMMs (LDS-staged, 4x8 acc/lane), CSR-based
// conv gather (no float atomics), bf16 h2 + LDS-staged gathered edge MLP.
// ---------------------------------------------------------------------------

__device__ __forceinline__ unsigned short f2bf(float f) {
    unsigned u = __float_as_uint(f);
    u += 0x7fff + ((u >> 16) & 1);  // round to nearest even
    return (unsigned short)(u >> 16);
}
__device__ __forceinline__ float bflo(unsigned d) { return __uint_as_float(d << 16); }
__device__ __forceinline__ float bfhi(unsigned d) { return __uint_as_float(d & 0xffff0000u); }

// ---- index dtype detection: flag=1 -> int32, 0 -> int64 --------------------
__global__ void detect_idx_k(const unsigned int* __restrict__ ei, int* __restrict__ flag) {
    int nz = 0;
    for (int i = threadIdx.x; i < 2048; i += 64)
        if (ei[2 * i + 1] != 0u) nz = 1;
    unsigned long long m = __ballot(nz);
    if (threadIdx.x == 0) *flag = (m != 0ull) ? 1 : 0;
}

__global__ void cvt_idx_k(const void* __restrict__ ei, const int* __restrict__ flag,
                          int* __restrict__ out, int n) {
    int i = blockIdx.x * 256 + threadIdx.x;
    if (i >= n) return;
    if (*flag) out[i] = ((const int*)ei)[i];
    else       out[i] = (int)((const long long*)ei)[i];
}

// ---- CSR build -------------------------------------------------------------
__global__ void deg_i_k(const int* __restrict__ dst, int* __restrict__ deg, int E) {
    int i = blockIdx.x * 256 + threadIdx.x;
    if (i < E) atomicAdd(&deg[dst[i]], 1);
}

__global__ void scan_blk_k(const int* __restrict__ deg, int* __restrict__ part,
                           int* __restrict__ bsum, int n1) {
    __shared__ int s[256];
    int t = threadIdx.x;
    int i = blockIdx.x * 256 + t;
    int v = (i < n1) ? deg[i] : 0;
    s[t] = v;
    __syncthreads();
    for (int o = 1; o < 256; o <<= 1) {
        int x = (t >= o) ? s[t - o] : 0;
        __syncthreads();
        s[t] += x;
        __syncthreads();
    }
    if (i < n1) part[i] = s[t] - v;  // exclusive
    if (t == 255) bsum[blockIdx.x] = s[255];
}

__global__ void scan_tot_k(int* __restrict__ bsum, int nb) {
    __shared__ int s[512];
    int t = threadIdx.x;
    int v = (t < nb) ? bsum[t] : 0;
    s[t] = v;
    __syncthreads();
    for (int o = 1; o < 512; o <<= 1) {
        int x = (t >= o) ? s[t - o] : 0;
        __syncthreads();
        s[t] += x;
        __syncthreads();
    }
    if (t < nb) bsum[t] = s[t] - v;  // exclusive block offsets
}

__global__ void scan_add_k(const int* __restrict__ part, const int* __restrict__ bsum,
                           int* __restrict__ rowptr, int n1) {
    int i = blockIdx.x * 256 + threadIdx.x;
    if (i < n1) rowptr[i] = part[i] + bsum[blockIdx.x];
}

__global__ void dinv_k(const int* __restrict__ deg, float* __restrict__ dinv, int n) {
    int i = blockIdx.x * 256 + threadIdx.x;
    if (i < n) dinv[i] = rsqrtf((float)deg[i] + 1.0f);  // +1 self-loop
}

__global__ void fill_csr_k(const int* __restrict__ src, const int* __restrict__ dst,
                           const int* __restrict__ rowptr, int* __restrict__ cursor,
                           int* __restrict__ csr, int E) {
    int e = blockIdx.x * 256 + threadIdx.x;
    if (e >= E) return;
    int d = dst[e];
    int pos = rowptr[d] + atomicAdd(&cursor[d], 1);
    csr[pos] = src[e];
}

// ---- register-tiled GEMM: C[n,64] = act(A[n,K] @ W[K,64] (+b)) -------------
// block = 256 thr (4 waves), tile = 128 rows x 64 cols; wave tile 32x64;
// lane (ri=lane>>3, ji=lane&7): rows wave*32+ri+8m (m<4), cols ji+8c (c<8).
template <int K, bool BIAS, bool RELU>
__global__ __launch_bounds__(256) void lin_tile_k(
    const float* __restrict__ A, const float* __restrict__ W,
    const float* __restrict__ b, float* __restrict__ C, int n) {
    constexpr int KP = K + 4;  // stride: %4==0 (b128 align), %32==4 (bank-distinct)
    __shared__ float As[128 * KP];
    __shared__ float Ws[64 * KP];
    int t = threadIdx.x;
    // stage A tile (row-major, float4)
    constexpr int K4 = K / 4;
    for (int i = t; i < 128 * K4; i += 256) {
        int r = i / K4, c4 = i % K4;
        int row = blockIdx.x * 128 + r;
        row = row < n ? row : n - 1;
        *(float4*)&As[r * KP + c4 * 4] = *(const float4*)&A[(size_t)row * K + c4 * 4];
    }
    // stage W transposed: Ws[j*KP + k] = W[k*64 + j]
    for (int i = t; i < K * 64; i += 256) {
        int k = i >> 6, j = i & 63;
        Ws[j * KP + k] = W[i];
    }
    __syncthreads();
    int lane = t & 63;
    int wave = t >> 6;
    int ri = lane >> 3, ji = lane & 7;
    float acc[4][8];
#pragma unroll
    for (int m = 0; m < 4; m++)
#pragma unroll
        for (int c = 0; c < 8; c++) acc[m][c] = BIAS ? b[ji + 8 * c] : 0.0f;
#pragma unroll
    for (int kc = 0; kc < K; kc += 4) {
        float4 a[4], w[8];
#pragma unroll
        for (int m = 0; m < 4; m++)
            a[m] = *(const float4*)&As[(wave * 32 + ri + 8 * m) * KP + kc];
#pragma unroll
        for (int c = 0; c < 8; c++)
            w[c] = *(const float4*)&Ws[(ji + 8 * c) * KP + kc];
#pragma unroll
        for (int m = 0; m < 4; m++)
#pragma unroll
            for (int c = 0; c < 8; c++) {
                acc[m][c] = fmaf(a[m].x, w[c].x, acc[m][c]);
                acc[m][c] = fmaf(a[m].y, w[c].y, acc[m][c]);
                acc[m][c] = fmaf(a[m].z, w[c].z, acc[m][c]);
                acc[m][c] = fmaf(a[m].w, w[c].w, acc[m][c]);
            }
    }
#pragma unroll
    for (int m = 0; m < 4; m++) {
        int row = blockIdx.x * 128 + wave * 32 + ri + 8 * m;
        if (row < n) {
#pragma unroll
            for (int c = 0; c < 8; c++) {
                float v = acc[m][c];
                if (RELU) v = fmaxf(v, 0.0f);
                C[(size_t)row * 64 + ji + 8 * c] = v;
            }
        }
    }
}

// ---- conv gather: out[d] = relu((sum_{e->d} hW[s]*dinv[s] + hW[d]*dv)*dv + b)
template <bool BF16OUT>
__global__ __launch_bounds__(256) void conv_gather_k(
    const float* __restrict__ hW, const float* __restrict__ dinv,
    const int* __restrict__ rowptr, const int* __restrict__ csr,
    const float* __restrict__ b, void* __restrict__ outv, int n) {
    int lane = threadIdx.x & 63;
    int wave = threadIdx.x >> 6;
    int node = blockIdx.x * 4 + wave;
    if (node >= n) return;
    int beg = rowptr[node], end = rowptr[node + 1];
    float dv = dinv[node];
    float acc = hW[(size_t)node * 64 + lane] * dv;  // self-loop (x dv again below)
    int i = beg;
    for (; i + 4 <= end; i += 4) {
        int s0 = csr[i], s1 = csr[i + 1], s2 = csr[i + 2], s3 = csr[i + 3];
        float w0 = dinv[s0], w1 = dinv[s1], w2 = dinv[s2], w3 = dinv[s3];
        float h0 = hW[(size_t)s0 * 64 + lane];
        float h1 = hW[(size_t)s1 * 64 + lane];
        float h2 = hW[(size_t)s2 * 64 + lane];
        float h3 = hW[(size_t)s3 * 64 + lane];
        acc = fmaf(h0, w0, acc);
        acc = fmaf(h1, w1, acc);
        acc = fmaf(h2, w2, acc);
        acc = fmaf(h3, w3, acc);
    }
    for (; i < end; i++) {
        int s = csr[i];
        acc = fmaf(hW[(size_t)s * 64 + lane], dinv[s], acc);
    }
    float v = fmaxf(fmaf(acc, dv, b[lane]), 0.0f);
    if (BF16OUT) ((unsigned short*)outv)[(size_t)node * 64 + lane] = f2bf(v);
    else         ((float*)outv)[(size_t)node * 64 + lane] = v;
}

// ---- edge MLP: out[e] = relu([h[s],h[d],attr] @ W1 + b1) . W2 + b2 ---------
// h in bf16. Block tile 128 edges; LDS Ab bf16 [128 x 152], Ws fp32 [64 x 140].
__global__ __launch_bounds__(256) void edge_mlp_k(
    const unsigned short* __restrict__ hb, const float* __restrict__ attr,
    const int* __restrict__ src, const int* __restrict__ dst,
    const float* __restrict__ W1, const float* __restrict__ b1,
    const float* __restrict__ W2, const float* __restrict__ b2,
    float* __restrict__ out, int E) {
    constexpr int AP = 152;  // halfs; *2B: %16==0 (uint4 store), bank step 12 (distinct)
    constexpr int WP = 140;  // floats; %4==0, bank step 12 (distinct)
    __shared__ unsigned short Ab[128 * AP];
    __shared__ float Ws[64 * WP];
    int t = threadIdx.x;
    int eb = blockIdx.x * 128;
    // stage gathered h rows (bf16, 16B chunks, per-lane coalesced)
    const uint4* hb4 = (const uint4*)hb;
    for (int i = t; i < 128 * 16; i += 256) {
        int r = i >> 4, ch = i & 15;
        int e = eb + r; e = e < E ? e : E - 1;
        int sd = (ch < 8) ? src[e] : dst[e];
        *(uint4*)&Ab[r * AP + ch * 8] = hb4[(size_t)sd * 8 + (ch & 7)];
    }
    // stage edge attrs (fp32 -> bf16)
    if (t < 128) {
        int e = eb + t; e = e < E ? e : E - 1;
        const float4* at4 = (const float4*)attr;
        float4 a0 = at4[(size_t)e * 2], a1 = at4[(size_t)e * 2 + 1];
        uint4 u;
        u.x = f2bf(a0.x) | ((unsigned)f2bf(a0.y) << 16);
        u.y = f2bf(a0.z) | ((unsigned)f2bf(a0.w) << 16);
        u.z = f2bf(a1.x) | ((unsigned)f2bf(a1.y) << 16);
        u.w = f2bf(a1.z) | ((unsigned)f2bf(a1.w) << 16);
        *(uint4*)&Ab[t * AP + 128] = u;
    }
    // stage W1 transposed: Ws[j*WP + k] = W1[k*64 + j]
    for (int i = t; i < 136 * 64; i += 256) {
        int k = i >> 6, j = i & 63;
        Ws[j * WP + k] = W1[i];
    }
    __syncthreads();
    int lane = t & 63;
    int wave = t >> 6;
    int ri = lane >> 3, ji = lane & 7;
    float bj[8], wj[8];
#pragma unroll
    for (int c = 0; c < 8; c++) {
        bj[c] = b1[ji + 8 * c];
        wj[c] = W2[ji + 8 * c];
    }
    float b2v = b2[0];
    float acc[4][8];
#pragma unroll
    for (int m = 0; m < 4; m++)
#pragma unroll
        for (int c = 0; c < 8; c++) acc[m][c] = bj[c];
    for (int kc = 0; kc < 136; kc += 4) {
        float a[4][4];
        float4 w[8];
#pragma unroll
        for (int m = 0; m < 4; m++) {
            uint2 q = *(const uint2*)&Ab[(wave * 32 + ri + 8 * m) * AP + kc];
            a[m][0] = bflo(q.x); a[m][1] = bfhi(q.x);
            a[m][2] = bflo(q.y); a[m][3] = bfhi(q.y);
        }
#pragma unroll
        for (int c = 0; c < 8; c++)
            w[c] = *(const float4*)&Ws[(ji + 8 * c) * WP + kc];
#pragma unroll
        for (int m = 0; m < 4; m++)
#pragma unroll
            for (int c = 0; c < 8; c++) {
                acc[m][c] = fmaf(a[m][0], w[c].x, acc[m][c]);
                acc[m][c] = fmaf(a[m][1], w[c].y, acc[m][c]);
                acc[m][c] = fmaf(a[m][2], w[c].z, acc[m][c]);
                acc[m][c] = fmaf(a[m][3], w[c].w, acc[m][c]);
            }
    }
    // layer 2: relu(z) . W2, reduce over 8 ji lanes (lanes ri*8..ri*8+7)
#pragma unroll
    for (int m = 0; m < 4; m++) {
        float v = 0.0f;
#pragma unroll
        for (int c = 0; c < 8; c++) v = fmaf(fmaxf(acc[m][c], 0.0f), wj[c], v);
        v += __shfl_xor(v, 1);
        v += __shfl_xor(v, 2);
        v += __shfl_xor(v, 4);
        if (ji == 0) {
            int e = eb + wave * 32 + ri + 8 * m;
            if (e < E) out[e] = v + b2v;
        }
    }
}

extern "C" void kernel_launch(void* const* d_in, const int* in_sizes, int n_in,
                              void* d_out, int out_size, void* d_ws, size_t ws_size,
                              hipStream_t stream) {
    const float* x    = (const float*)d_in[0];
    const float* attr = (const float*)d_in[1];
    const float* W_e  = (const float*)d_in[2];
    const float* b_e  = (const float*)d_in[3];
    const float* W_c1 = (const float*)d_in[4];
    const float* b_c1 = (const float*)d_in[5];
    const float* W_c2 = (const float*)d_in[6];
    const float* b_c2 = (const float*)d_in[7];
    const float* W_p1 = (const float*)d_in[8];
    const float* b_p1 = (const float*)d_in[9];
    const float* W_p2 = (const float*)d_in[10];
    const float* b_p2 = (const float*)d_in[11];
    const void*  ei   = d_in[12];
    int N = in_sizes[0] / 32;
    int E = in_sizes[1] / 8;
    int n1 = N + 1;
    float* out = (float*)d_out;

    char* p = (char*)d_ws;
    auto alloc = [&](size_t bytes) { void* q = p; p += (bytes + 255) & ~(size_t)255; return q; };
    float* A            = (float*)alloc((size_t)N * 64 * 4);
    float* B            = (float*)alloc((size_t)N * 64 * 4);
    unsigned short* hb  = (unsigned short*)alloc((size_t)N * 64 * 2);
    float* dinv         = (float*)alloc((size_t)N * 4);
    int* srcI           = (int*)alloc((size_t)E * 4);
    int* dstI           = (int*)alloc((size_t)E * 4);
    int* csr            = (int*)alloc((size_t)E * 4);
    int* deg            = (int*)alloc((size_t)n1 * 4);
    int* rowptr         = (int*)alloc((size_t)n1 * 4);
    int* part           = (int*)alloc((size_t)n1 * 4);
    int* bsum           = (int*)alloc(512 * 4);
    int* flag           = (int*)alloc(4);
    int* cursor = part;  // part is dead after scan_add

    auto cdiv = [](long long a, long long b) { return (int)((a + b - 1) / b); };

    // indices -> int32
    detect_idx_k<<<1, 64, 0, stream>>>((const unsigned int*)ei, flag);
    cvt_idx_k<<<cdiv(2LL * E, 256), 256, 0, stream>>>(ei, flag, srcI, 2 * E);
    // CSR build
    hipMemsetAsync(deg, 0, (size_t)n1 * 4, stream);
    deg_i_k<<<cdiv(E, 256), 256, 0, stream>>>(dstI, deg, E);
    int nb = cdiv(n1, 256);
    scan_blk_k<<<nb, 256, 0, stream>>>(deg, part, bsum, n1);
    scan_tot_k<<<1, 512, 0, stream>>>(bsum, nb);
    scan_add_k<<<nb, 256, 0, stream>>>(part, bsum, rowptr, n1);
    dinv_k<<<cdiv(N, 256), 256, 0, stream>>>(deg, dinv, N);
    hipMemsetAsync(cursor, 0, (size_t)N * 4, stream);
    fill_csr_k<<<cdiv(E, 256), 256, 0, stream>>>(srcI, dstI, rowptr, cursor, csr, E);
    // network
    int lg = cdiv(N, 128);
    lin_tile_k<32, true, true><<<lg, 256, 0, stream>>>(x, W_e, b_e, A, N);          // h0 -> A
    lin_tile_k<64, false, false><<<lg, 256, 0, stream>>>(A, W_c1, nullptr, B, N);   // hW1 -> B
    conv_gather_k<false><<<cdiv(N, 4), 256, 0, stream>>>(B, dinv, rowptr, csr, b_c1, A, N);  // h1 -> A
    lin_tile_k<64, false, false><<<lg, 256, 0, stream>>>(A, W_c2, nullptr, B, N);   // hW2 -> B
    conv_gather_k<true><<<cdiv(N, 4), 256, 0, stream>>>(B, dinv, rowptr, csr, b_c2, hb, N);  // h2 -> hb (bf16)
    edge_mlp_k<<<cdiv(E, 128), 256, 0, stream>>>(hb, attr, srcI, dstI, W_p1, b_p1, W_p2, b_p2, out, E);
}

// Round 3
// 1227.259 us; speedup vs baseline: 4.3428x; 1.1985x over previous
//
#include <hip/hip_runtime.h>
#include <hip/hip_fp16.h>

// ---------------------------------------------------------------------------
// GNN traffic predictor: embed -> GCNConv x2 -> edge MLP
// N=100000, E=1600000, F_NODE=32, F_EDGE=8, H=64
// Round 3: edge MLP on matrix cores (mfma_f32_16x16x32_f16), fp16 h2/attr/W1;
// fp32 register-tiled lin GEMMs + CSR conv gather unchanged from round 2.
// ---------------------------------------------------------------------------

typedef __attribute__((ext_vector_type(8))) _Float16 half8;
typedef __attribute__((ext_vector_type(4))) float f32x4;

__device__ __forceinline__ unsigned short f2h(float f) {
    return __half_as_ushort(__float2half(f));
}
__device__ __forceinline__ unsigned ph2(float a, float b) {
    return (unsigned)f2h(a) | ((unsigned)f2h(b) << 16);
}

// ---- index dtype detection: flag=1 -> int32, 0 -> int64 --------------------
__global__ void detect_idx_k(const unsigned int* __restrict__ ei, int* __restrict__ flag) {
    int nz = 0;
    for (int i = threadIdx.x; i < 2048; i += 64)
        if (ei[2 * i + 1] != 0u) nz = 1;
    unsigned long long m = __ballot(nz);
    if (threadIdx.x == 0) *flag = (m != 0ull) ? 1 : 0;
}

__global__ void cvt_idx_k(const void* __restrict__ ei, const int* __restrict__ flag,
                          int* __restrict__ out, int n) {
    int i = blockIdx.x * 256 + threadIdx.x;
    if (i >= n) return;
    if (*flag) out[i] = ((const int*)ei)[i];
    else       out[i] = (int)((const long long*)ei)[i];
}

// ---- CSR build -------------------------------------------------------------
__global__ void deg_i_k(const int* __restrict__ dst, int* __restrict__ deg, int E) {
    int i = blockIdx.x * 256 + threadIdx.x;
    if (i < E) atomicAdd(&deg[dst[i]], 1);
}

__global__ void scan_blk_k(const int* __restrict__ deg, int* __restrict__ part,
                           int* __restrict__ bsum, int n1) {
    __shared__ int s[256];
    int t = threadIdx.x;
    int i = blockIdx.x * 256 + t;
    int v = (i < n1) ? deg[i] : 0;
    s[t] = v;
    __syncthreads();
    for (int o = 1; o < 256; o <<= 1) {
        int x = (t >= o) ? s[t - o] : 0;
        __syncthreads();
        s[t] += x;
        __syncthreads();
    }
    if (i < n1) part[i] = s[t] - v;  // exclusive
    if (t == 255) bsum[blockIdx.x] = s[255];
}

__global__ void scan_tot_k(int* __restrict__ bsum, int nb) {
    __shared__ int s[512];
    int t = threadIdx.x;
    int v = (t < nb) ? bsum[t] : 0;
    s[t] = v;
    __syncthreads();
    for (int o = 1; o < 512; o <<= 1) {
        int x = (t >= o) ? s[t - o] : 0;
        __syncthreads();
        s[t] += x;
        __syncthreads();
    }
    if (t < nb) bsum[t] = s[t] - v;  // exclusive block offsets
}

__global__ void scan_add_k(const int* __restrict__ part, const int* __restrict__ bsum,
                           int* __restrict__ rowptr, int n1) {
    int i = blockIdx.x * 256 + threadIdx.x;
    if (i < n1) rowptr[i] = part[i] + bsum[blockIdx.x];
}

__global__ void dinv_k(const int* __restrict__ deg, float* __restrict__ dinv, int n) {
    int i = blockIdx.x * 256 + threadIdx.x;
    if (i < n) dinv[i] = rsqrtf((float)deg[i] + 1.0f);  // +1 self-loop
}

__global__ void fill_csr_k(const int* __restrict__ src, const int* __restrict__ dst,
                           const int* __restrict__ rowptr, int* __restrict__ cursor,
                           int* __restrict__ csr, int E) {
    int e = blockIdx.x * 256 + threadIdx.x;
    if (e >= E) return;
    int d = dst[e];
    int pos = rowptr[d] + atomicAdd(&cursor[d], 1);
    csr[pos] = src[e];
}

// ---- W1 -> fp16 transposed, padded [64][168], zero K-tail ------------------
__global__ void prep_w1_k(const float* __restrict__ W1, unsigned short* __restrict__ W1t) {
    int i = blockIdx.x * 256 + threadIdx.x;
    if (i >= 64 * 168) return;
    int n = i / 168, k = i % 168;
    float v = (k < 136) ? W1[k * 64 + n] : 0.0f;
    W1t[i] = f2h(v);
}

// ---- register-tiled GEMM: C[n,64] = act(A[n,K] @ W[K,64] (+b)) -------------
template <int K, bool BIAS, bool RELU>
__global__ __launch_bounds__(256) void lin_tile_k(
    const float* __restrict__ A, const float* __restrict__ W,
    const float* __restrict__ b, float* __restrict__ C, int n) {
    constexpr int KP = K + 4;
    __shared__ float As[128 * KP];
    __shared__ float Ws[64 * KP];
    int t = threadIdx.x;
    constexpr int K4 = K / 4;
    for (int i = t; i < 128 * K4; i += 256) {
        int r = i / K4, c4 = i % K4;
        int row = blockIdx.x * 128 + r;
        row = row < n ? row : n - 1;
        *(float4*)&As[r * KP + c4 * 4] = *(const float4*)&A[(size_t)row * K + c4 * 4];
    }
    for (int i = t; i < K * 64; i += 256) {
        int k = i >> 6, j = i & 63;
        Ws[j * KP + k] = W[i];
    }
    __syncthreads();
    int lane = t & 63;
    int wave = t >> 6;
    int ri = lane >> 3, ji = lane & 7;
    float acc[4][8];
#pragma unroll
    for (int m = 0; m < 4; m++)
#pragma unroll
        for (int c = 0; c < 8; c++) acc[m][c] = BIAS ? b[ji + 8 * c] : 0.0f;
#pragma unroll
    for (int kc = 0; kc < K; kc += 4) {
        float4 a[4], w[8];
#pragma unroll
        for (int m = 0; m < 4; m++)
            a[m] = *(const float4*)&As[(wave * 32 + ri + 8 * m) * KP + kc];
#pragma unroll
        for (int c = 0; c < 8; c++)
            w[c] = *(const float4*)&Ws[(ji + 8 * c) * KP + kc];
#pragma unroll
        for (int m = 0; m < 4; m++)
#pragma unroll
            for (int c = 0; c < 8; c++) {
                acc[m][c] = fmaf(a[m].x, w[c].x, acc[m][c]);
                acc[m][c] = fmaf(a[m].y, w[c].y, acc[m][c]);
                acc[m][c] = fmaf(a[m].z, w[c].z, acc[m][c]);
                acc[m][c] = fmaf(a[m].w, w[c].w, acc[m][c]);
            }
    }
#pragma unroll
    for (int m = 0; m < 4; m++) {
        int row = blockIdx.x * 128 + wave * 32 + ri + 8 * m;
        if (row < n) {
#pragma unroll
            for (int c = 0; c < 8; c++) {
                float v = acc[m][c];
                if (RELU) v = fmaxf(v, 0.0f);
                C[(size_t)row * 64 + ji + 8 * c] = v;
            }
        }
    }
}

// ---- conv gather: out[d] = relu((sum_{e->d} hW[s]*dinv[s] + hW[d]*dv)*dv + b)
template <bool HALFOUT>
__global__ __launch_bounds__(256) void conv_gather_k(
    const float* __restrict__ hW, const float* __restrict__ dinv,
    const int* __restrict__ rowptr, const int* __restrict__ csr,
    const float* __restrict__ b, void* __restrict__ outv, int n) {
    int lane = threadIdx.x & 63;
    int wave = threadIdx.x >> 6;
    int node = blockIdx.x * 4 + wave;
    if (node >= n) return;
    int beg = rowptr[node], end = rowptr[node + 1];
    float dv = dinv[node];
    float acc = hW[(size_t)node * 64 + lane] * dv;  // self-loop
    int i = beg;
    for (; i + 4 <= end; i += 4) {
        int s0 = csr[i], s1 = csr[i + 1], s2 = csr[i + 2], s3 = csr[i + 3];
        float w0 = dinv[s0], w1 = dinv[s1], w2 = dinv[s2], w3 = dinv[s3];
        float h0 = hW[(size_t)s0 * 64 + lane];
        float h1 = hW[(size_t)s1 * 64 + lane];
        float h2 = hW[(size_t)s2 * 64 + lane];
        float h3 = hW[(size_t)s3 * 64 + lane];
        acc = fmaf(h0, w0, acc);
        acc = fmaf(h1, w1, acc);
        acc = fmaf(h2, w2, acc);
        acc = fmaf(h3, w3, acc);
    }
    for (; i < end; i++) {
        int s = csr[i];
        acc = fmaf(hW[(size_t)s * 64 + lane], dinv[s], acc);
    }
    float v = fmaxf(fmaf(acc, dv, b[lane]), 0.0f);
    if (HALFOUT) ((unsigned short*)outv)[(size_t)node * 64 + lane] = f2h(v);
    else         ((float*)outv)[(size_t)node * 64 + lane] = v;
}

// ---- edge MLP via MFMA -----------------------------------------------------
// out[e] = relu([h[s],h[d],attr] @ W1 + b1) . W2 + b2; h fp16, W1 fp16.
// Block: 128-edge tile, 4 waves; wave handles 32 edge rows (2 M-tiles x 4 N-tiles).
// PA=168 halfs: 336B row = 84 words -> b128 frag reads are 2-way/bank (free).
#define PA 168
__global__ __launch_bounds__(256) void edge_mlp_mfma_k(
    const unsigned short* __restrict__ hb, const float* __restrict__ attr,
    const int* __restrict__ src, const int* __restrict__ dst,
    const unsigned short* __restrict__ W1t,  // [64][168] fp16, transposed+padded
    const float* __restrict__ b1, const float* __restrict__ W2,
    const float* __restrict__ b2, float* __restrict__ out, int E) {
    __shared__ __align__(16) unsigned short Ah[128 * PA];
    __shared__ __align__(16) unsigned short Wh[64 * PA];
    int t = threadIdx.x;
    int eb = blockIdx.x * 128;
    // stage W1t (flat uint4 copy: 64*168*2/16 = 1344)
    const uint4* wsrc = (const uint4*)W1t;
    uint4* wdst = (uint4*)Wh;
    for (int i = t; i < 1344; i += 256) wdst[i] = wsrc[i];
    // stage gathered h rows (fp16, 16B chunks, per-lane coalesced)
    const uint4* h4 = (const uint4*)hb;  // 8 chunks per 64-half row
    for (int i = t; i < 128 * 16; i += 256) {
        int r = i >> 4, ch = i & 15;
        int e = eb + r; e = e < E ? e : E - 1;
        int node = (ch < 8) ? src[e] : dst[e];
        int off = (ch < 8) ? ch * 8 : 64 + (ch - 8) * 8;
        *(uint4*)&Ah[r * PA + off] = h4[(size_t)node * 8 + (ch & 7)];
    }
    // stage attrs (fp32 -> fp16) + zero K-tail 136..159
    if (t < 128) {
        int e = eb + t; e = e < E ? e : E - 1;
        const float4* a4 = (const float4*)attr;
        float4 x0 = a4[(size_t)e * 2], x1 = a4[(size_t)e * 2 + 1];
        uint4 u;
        u.x = ph2(x0.x, x0.y); u.y = ph2(x0.z, x0.w);
        u.z = ph2(x1.x, x1.y); u.w = ph2(x1.z, x1.w);
        *(uint4*)&Ah[t * PA + 128] = u;
        uint4 z = {0u, 0u, 0u, 0u};
        *(uint4*)&Ah[t * PA + 136] = z;
        *(uint4*)&Ah[t * PA + 144] = z;
        *(uint4*)&Ah[t * PA + 152] = z;
    }
    __syncthreads();

    int lane = t & 63;
    int wave = t >> 6;
    int col = lane & 15;
    int quad = lane >> 4;
    float b1v[4], w2v[4];
#pragma unroll
    for (int nt = 0; nt < 4; nt++) {
        b1v[nt] = b1[nt * 16 + col];
        w2v[nt] = W2[nt * 16 + col];
    }
    f32x4 acc[2][4];
#pragma unroll
    for (int mt = 0; mt < 2; mt++)
#pragma unroll
        for (int nt = 0; nt < 4; nt++)
            acc[mt][nt] = (f32x4){b1v[nt], b1v[nt], b1v[nt], b1v[nt]};
#pragma unroll
    for (int kc = 0; kc < 160; kc += 32) {
        // A frag: A[m=lane&15][k=quad*8+j]; B frag: B[k=quad*8+j][n=lane&15]
        half8 a0 = *(const half8*)&Ah[(wave * 32 + col) * PA + kc + quad * 8];
        half8 a1 = *(const half8*)&Ah[(wave * 32 + 16 + col) * PA + kc + quad * 8];
        half8 bfr[4];
#pragma unroll
        for (int nt = 0; nt < 4; nt++)
            bfr[nt] = *(const half8*)&Wh[(nt * 16 + col) * PA + kc + quad * 8];
#pragma unroll
        for (int nt = 0; nt < 4; nt++) {
            acc[0][nt] = __builtin_amdgcn_mfma_f32_16x16x32_f16(a0, bfr[nt], acc[0][nt], 0, 0, 0);
            acc[1][nt] = __builtin_amdgcn_mfma_f32_16x16x32_f16(a1, bfr[nt], acc[1][nt], 0, 0, 0);
        }
    }
    // layer 2: relu(z) . W2; C/D layout col=lane&15, row=quad*4+reg
    float b2v = b2[0];
#pragma unroll
    for (int mt = 0; mt < 2; mt++)
#pragma unroll
        for (int reg = 0; reg < 4; reg++) {
            float p = 0.0f;
#pragma unroll
            for (int nt = 0; nt < 4; nt++)
                p = fmaf(fmaxf(acc[mt][nt][reg], 0.0f), w2v[nt], p);
            p += __shfl_xor(p, 1);
            p += __shfl_xor(p, 2);
            p += __shfl_xor(p, 4);
            p += __shfl_xor(p, 8);
            if (col == 0) {
                int e = eb + wave * 32 + mt * 16 + quad * 4 + reg;
                if (e < E) out[e] = p + b2v;
            }
        }
}

extern "C" void kernel_launch(void* const* d_in, const int* in_sizes, int n_in,
                              void* d_out, int out_size, void* d_ws, size_t ws_size,
                              hipStream_t stream) {
    const float* x    = (const float*)d_in[0];
    const float* attr = (const float*)d_in[1];
    const float* W_e  = (const float*)d_in[2];
    const float* b_e  = (const float*)d_in[3];
    const float* W_c1 = (const float*)d_in[4];
    const float* b_c1 = (const float*)d_in[5];
    const float* W_c2 = (const float*)d_in[6];
    const float* b_c2 = (const float*)d_in[7];
    const float* W_p1 = (const float*)d_in[8];
    const float* b_p1 = (const float*)d_in[9];
    const float* W_p2 = (const float*)d_in[10];
    const float* b_p2 = (const float*)d_in[11];
    const void*  ei   = d_in[12];
    int N = in_sizes[0] / 32;
    int E = in_sizes[1] / 8;
    int n1 = N + 1;
    float* out = (float*)d_out;

    char* p = (char*)d_ws;
    auto alloc = [&](size_t bytes) { void* q = p; p += (bytes + 255) & ~(size_t)255; return q; };
    float* A            = (float*)alloc((size_t)N * 64 * 4);
    float* B            = (float*)alloc((size_t)N * 64 * 4);
    unsigned short* hb  = (unsigned short*)alloc((size_t)N * 64 * 2);
    float* dinv         = (float*)alloc((size_t)N * 4);
    int* srcI           = (int*)alloc((size_t)E * 4);
    int* dstI           = (int*)alloc((size_t)E * 4);
    int* csr            = (int*)alloc((size_t)E * 4);
    int* deg            = (int*)alloc((size_t)n1 * 4);
    int* rowptr         = (int*)alloc((size_t)n1 * 4);
    int* part           = (int*)alloc((size_t)n1 * 4);
    int* bsum           = (int*)alloc(512 * 4);
    unsigned short* W1t = (unsigned short*)alloc(64 * 168 * 2);
    int* flag           = (int*)alloc(4);
    int* cursor = part;  // part is dead after scan_add

    auto cdiv = [](long long a, long long b) { return (int)((a + b - 1) / b); };

    // indices -> int32
    detect_idx_k<<<1, 64, 0, stream>>>((const unsigned int*)ei, flag);
    cvt_idx_k<<<cdiv(2LL * E, 256), 256, 0, stream>>>(ei, flag, srcI, 2 * E);
    // CSR build
    hipMemsetAsync(deg, 0, (size_t)n1 * 4, stream);
    deg_i_k<<<cdiv(E, 256), 256, 0, stream>>>(dstI, deg, E);
    int nb = cdiv(n1, 256);
    scan_blk_k<<<nb, 256, 0, stream>>>(deg, part, bsum, n1);
    scan_tot_k<<<1, 512, 0, stream>>>(bsum, nb);
    scan_add_k<<<nb, 256, 0, stream>>>(part, bsum, rowptr, n1);
    dinv_k<<<cdiv(N, 256), 256, 0, stream>>>(deg, dinv, N);
    hipMemsetAsync(cursor, 0, (size_t)N * 4, stream);
    fill_csr_k<<<cdiv(E, 256), 256, 0, stream>>>(srcI, dstI, rowptr, cursor, csr, E);
    prep_w1_k<<<cdiv(64 * 168, 256), 256, 0, stream>>>(W_p1, W1t);
    // network
    int lg = cdiv(N, 128);
    lin_tile_k<32, true, true><<<lg, 256, 0, stream>>>(x, W_e, b_e, A, N);          // h0 -> A
    lin_tile_k<64, false, false><<<lg, 256, 0, stream>>>(A, W_c1, nullptr, B, N);   // hW1 -> B
    conv_gather_k<false><<<cdiv(N, 4), 256, 0, stream>>>(B, dinv, rowptr, csr, b_c1, A, N);  // h1 -> A
    lin_tile_k<64, false, false><<<lg, 256, 0, stream>>>(A, W_c2, nullptr, B, N);   // hW2 -> B
    conv_gather_k<true><<<cdiv(N, 4), 256, 0, stream>>>(B, dinv, rowptr, csr, b_c2, hb, N);  // h2 -> hb (fp16)
    edge_mlp_mfma_k<<<cdiv(E, 128), 256, 0, stream>>>(hb, attr, srcI, dstI, W1t,
                                                      b_p1, W_p2, b_p2, out, E);
}

// Round 4
// 667.798 us; speedup vs baseline: 7.9810x; 1.8378x over previous
//
#include <hip/hip_runtime.h>
#include <hip/hip_fp16.h>

// ---------------------------------------------------------------------------
// GNN traffic predictor: embed -> GCNConv x2 -> edge MLP
// N=100000, E=1600000, F_NODE=32, F_EDGE=8, H=64
// Round 4: fix lin_tile_k register spills (launch_bounds cap + partial unroll,
// was 256 VGPR + 460MB scratch traffic); fp16 hW path halves conv gather
// traffic. Edge MLP on MFMA unchanged from round 3.
// ---------------------------------------------------------------------------

typedef __attribute__((ext_vector_type(8))) _Float16 half8;
typedef __attribute__((ext_vector_type(4))) float f32x4;

__device__ __forceinline__ unsigned short f2h(float f) {
    return __half_as_ushort(__float2half(f));
}
__device__ __forceinline__ float h2f(unsigned short u) {
    return __half2float(__ushort_as_half(u));
}
__device__ __forceinline__ unsigned ph2(float a, float b) {
    return (unsigned)f2h(a) | ((unsigned)f2h(b) << 16);
}

// ---- index dtype detection: flag=1 -> int32, 0 -> int64 --------------------
__global__ void detect_idx_k(const unsigned int* __restrict__ ei, int* __restrict__ flag) {
    int nz = 0;
    for (int i = threadIdx.x; i < 2048; i += 64)
        if (ei[2 * i + 1] != 0u) nz = 1;
    unsigned long long m = __ballot(nz);
    if (threadIdx.x == 0) *flag = (m != 0ull) ? 1 : 0;
}

__global__ void cvt_idx_k(const void* __restrict__ ei, const int* __restrict__ flag,
                          int* __restrict__ out, int n) {
    int i = blockIdx.x * 256 + threadIdx.x;
    if (i >= n) return;
    if (*flag) out[i] = ((const int*)ei)[i];
    else       out[i] = (int)((const long long*)ei)[i];
}

// ---- CSR build -------------------------------------------------------------
__global__ void deg_i_k(const int* __restrict__ dst, int* __restrict__ deg, int E) {
    int i = blockIdx.x * 256 + threadIdx.x;
    if (i < E) atomicAdd(&deg[dst[i]], 1);
}

__global__ void scan_blk_k(const int* __restrict__ deg, int* __restrict__ part,
                           int* __restrict__ bsum, int n1) {
    __shared__ int s[256];
    int t = threadIdx.x;
    int i = blockIdx.x * 256 + t;
    int v = (i < n1) ? deg[i] : 0;
    s[t] = v;
    __syncthreads();
    for (int o = 1; o < 256; o <<= 1) {
        int x = (t >= o) ? s[t - o] : 0;
        __syncthreads();
        s[t] += x;
        __syncthreads();
    }
    if (i < n1) part[i] = s[t] - v;  // exclusive
    if (t == 255) bsum[blockIdx.x] = s[255];
}

__global__ void scan_tot_k(int* __restrict__ bsum, int nb) {
    __shared__ int s[512];
    int t = threadIdx.x;
    int v = (t < nb) ? bsum[t] : 0;
    s[t] = v;
    __syncthreads();
    for (int o = 1; o < 512; o <<= 1) {
        int x = (t >= o) ? s[t - o] : 0;
        __syncthreads();
        s[t] += x;
        __syncthreads();
    }
    if (t < nb) bsum[t] = s[t] - v;  // exclusive block offsets
}

__global__ void scan_add_k(const int* __restrict__ part, const int* __restrict__ bsum,
                           int* __restrict__ rowptr, int n1) {
    int i = blockIdx.x * 256 + threadIdx.x;
    if (i < n1) rowptr[i] = part[i] + bsum[blockIdx.x];
}

__global__ void dinv_k(const int* __restrict__ deg, float* __restrict__ dinv, int n) {
    int i = blockIdx.x * 256 + threadIdx.x;
    if (i < n) dinv[i] = rsqrtf((float)deg[i] + 1.0f);  // +1 self-loop
}

__global__ void fill_csr_k(const int* __restrict__ src, const int* __restrict__ dst,
                           const int* __restrict__ rowptr, int* __restrict__ cursor,
                           int* __restrict__ csr, int E) {
    int e = blockIdx.x * 256 + threadIdx.x;
    if (e >= E) return;
    int d = dst[e];
    int pos = rowptr[d] + atomicAdd(&cursor[d], 1);
    csr[pos] = src[e];
}

// ---- W1 -> fp16 transposed, padded [64][168], zero K-tail ------------------
__global__ void prep_w1_k(const float* __restrict__ W1, unsigned short* __restrict__ W1t) {
    int i = blockIdx.x * 256 + threadIdx.x;
    if (i >= 64 * 168) return;
    int n = i / 168, k = i % 168;
    float v = (k < 136) ? W1[k * 64 + n] : 0.0f;
    W1t[i] = f2h(v);
}

// ---- register-tiled GEMM: C[n,64] = act(A[n,K] @ W[K,64] (+b)) -------------
// launch_bounds(256,4): cap 128 VGPRs (round-3 had 256 + spills -> 460MB
// scratch traffic, 288us; true live set ~110 regs with unroll 2).
template <int K, bool BIAS, bool RELU, bool F16OUT>
__global__ __launch_bounds__(256, 4) void lin_tile_k(
    const float* __restrict__ A, const float* __restrict__ W,
    const float* __restrict__ b, void* __restrict__ outv, int n) {
    constexpr int KP = K + 4;
    __shared__ float As[128 * KP];
    __shared__ float Ws[64 * KP];
    int t = threadIdx.x;
    constexpr int K4 = K / 4;
    for (int i = t; i < 128 * K4; i += 256) {
        int r = i / K4, c4 = i % K4;
        int row = blockIdx.x * 128 + r;
        row = row < n ? row : n - 1;
        *(float4*)&As[r * KP + c4 * 4] = *(const float4*)&A[(size_t)row * K + c4 * 4];
    }
    for (int i = t; i < K * 64; i += 256) {
        int k = i >> 6, j = i & 63;
        Ws[j * KP + k] = W[i];
    }
    __syncthreads();
    int lane = t & 63;
    int wave = t >> 6;
    int ri = lane >> 3, ji = lane & 7;
    float acc[4][8];
#pragma unroll
    for (int m = 0; m < 4; m++)
#pragma unroll
        for (int c = 0; c < 8; c++) acc[m][c] = BIAS ? b[ji + 8 * c] : 0.0f;
#pragma unroll 2
    for (int kc = 0; kc < K; kc += 4) {
        float4 a[4], w[8];
#pragma unroll
        for (int m = 0; m < 4; m++)
            a[m] = *(const float4*)&As[(wave * 32 + ri + 8 * m) * KP + kc];
#pragma unroll
        for (int c = 0; c < 8; c++)
            w[c] = *(const float4*)&Ws[(ji + 8 * c) * KP + kc];
#pragma unroll
        for (int m = 0; m < 4; m++)
#pragma unroll
            for (int c = 0; c < 8; c++) {
                acc[m][c] = fmaf(a[m].x, w[c].x, acc[m][c]);
                acc[m][c] = fmaf(a[m].y, w[c].y, acc[m][c]);
                acc[m][c] = fmaf(a[m].z, w[c].z, acc[m][c]);
                acc[m][c] = fmaf(a[m].w, w[c].w, acc[m][c]);
            }
    }
#pragma unroll
    for (int m = 0; m < 4; m++) {
        int row = blockIdx.x * 128 + wave * 32 + ri + 8 * m;
        if (row < n) {
#pragma unroll
            for (int c = 0; c < 8; c++) {
                float v = acc[m][c];
                if (RELU) v = fmaxf(v, 0.0f);
                if (F16OUT) ((unsigned short*)outv)[(size_t)row * 64 + ji + 8 * c] = f2h(v);
                else        ((float*)outv)[(size_t)row * 64 + ji + 8 * c] = v;
            }
        }
    }
}

// ---- conv gather: out[d] = relu((sum_{e->d} hW[s]*dinv[s] + hW[d]*dv)*dv + b)
// hW in fp16 (halves gather traffic vs fp32); fp32 accumulation.
template <bool F16OUT>
__global__ __launch_bounds__(256) void conv_gather_k(
    const unsigned short* __restrict__ hW, const float* __restrict__ dinv,
    const int* __restrict__ rowptr, const int* __restrict__ csr,
    const float* __restrict__ b, void* __restrict__ outv, int n) {
    int lane = threadIdx.x & 63;
    int wave = threadIdx.x >> 6;
    int node = blockIdx.x * 4 + wave;
    if (node >= n) return;
    int beg = rowptr[node], end = rowptr[node + 1];
    float dv = dinv[node];
    float acc = h2f(hW[(size_t)node * 64 + lane]) * dv;  // self-loop
    int i = beg;
    for (; i + 4 <= end; i += 4) {
        int s0 = csr[i], s1 = csr[i + 1], s2 = csr[i + 2], s3 = csr[i + 3];
        float w0 = dinv[s0], w1 = dinv[s1], w2 = dinv[s2], w3 = dinv[s3];
        float h0 = h2f(hW[(size_t)s0 * 64 + lane]);
        float h1 = h2f(hW[(size_t)s1 * 64 + lane]);
        float h2 = h2f(hW[(size_t)s2 * 64 + lane]);
        float h3 = h2f(hW[(size_t)s3 * 64 + lane]);
        acc = fmaf(h0, w0, acc);
        acc = fmaf(h1, w1, acc);
        acc = fmaf(h2, w2, acc);
        acc = fmaf(h3, w3, acc);
    }
    for (; i < end; i++) {
        int s = csr[i];
        acc = fmaf(h2f(hW[(size_t)s * 64 + lane]), dinv[s], acc);
    }
    float v = fmaxf(fmaf(acc, dv, b[lane]), 0.0f);
    if (F16OUT) ((unsigned short*)outv)[(size_t)node * 64 + lane] = f2h(v);
    else        ((float*)outv)[(size_t)node * 64 + lane] = v;
}

// ---- edge MLP via MFMA -----------------------------------------------------
// out[e] = relu([h[s],h[d],attr] @ W1 + b1) . W2 + b2; h fp16, W1 fp16.
// Block: 128-edge tile, 4 waves; wave handles 32 edge rows (2 M x 4 N tiles).
#define PA 168
__global__ __launch_bounds__(256) void edge_mlp_mfma_k(
    const unsigned short* __restrict__ hb, const float* __restrict__ attr,
    const int* __restrict__ src, const int* __restrict__ dst,
    const unsigned short* __restrict__ W1t,  // [64][168] fp16, transposed+padded
    const float* __restrict__ b1, const float* __restrict__ W2,
    const float* __restrict__ b2, float* __restrict__ out, int E) {
    __shared__ __align__(16) unsigned short Ah[128 * PA];
    __shared__ __align__(16) unsigned short Wh[64 * PA];
    int t = threadIdx.x;
    int eb = blockIdx.x * 128;
    const uint4* wsrc = (const uint4*)W1t;
    uint4* wdst = (uint4*)Wh;
    for (int i = t; i < 1344; i += 256) wdst[i] = wsrc[i];
    const uint4* h4 = (const uint4*)hb;  // 8 chunks per 64-half row
    for (int i = t; i < 128 * 16; i += 256) {
        int r = i >> 4, ch = i & 15;
        int e = eb + r; e = e < E ? e : E - 1;
        int node = (ch < 8) ? src[e] : dst[e];
        int off = (ch < 8) ? ch * 8 : 64 + (ch - 8) * 8;
        *(uint4*)&Ah[r * PA + off] = h4[(size_t)node * 8 + (ch & 7)];
    }
    if (t < 128) {
        int e = eb + t; e = e < E ? e : E - 1;
        const float4* a4 = (const float4*)attr;
        float4 x0 = a4[(size_t)e * 2], x1 = a4[(size_t)e * 2 + 1];
        uint4 u;
        u.x = ph2(x0.x, x0.y); u.y = ph2(x0.z, x0.w);
        u.z = ph2(x1.x, x1.y); u.w = ph2(x1.z, x1.w);
        *(uint4*)&Ah[t * PA + 128] = u;
        uint4 z = {0u, 0u, 0u, 0u};
        *(uint4*)&Ah[t * PA + 136] = z;
        *(uint4*)&Ah[t * PA + 144] = z;
        *(uint4*)&Ah[t * PA + 152] = z;
    }
    __syncthreads();

    int lane = t & 63;
    int wave = t >> 6;
    int col = lane & 15;
    int quad = lane >> 4;
    float b1v[4], w2v[4];
#pragma unroll
    for (int nt = 0; nt < 4; nt++) {
        b1v[nt] = b1[nt * 16 + col];
        w2v[nt] = W2[nt * 16 + col];
    }
    f32x4 acc[2][4];
#pragma unroll
    for (int mt = 0; mt < 2; mt++)
#pragma unroll
        for (int nt = 0; nt < 4; nt++)
            acc[mt][nt] = (f32x4){b1v[nt], b1v[nt], b1v[nt], b1v[nt]};
#pragma unroll
    for (int kc = 0; kc < 160; kc += 32) {
        half8 a0 = *(const half8*)&Ah[(wave * 32 + col) * PA + kc + quad * 8];
        half8 a1 = *(const half8*)&Ah[(wave * 32 + 16 + col) * PA + kc + quad * 8];
        half8 bfr[4];
#pragma unroll
        for (int nt = 0; nt < 4; nt++)
            bfr[nt] = *(const half8*)&Wh[(nt * 16 + col) * PA + kc + quad * 8];
#pragma unroll
        for (int nt = 0; nt < 4; nt++) {
            acc[0][nt] = __builtin_amdgcn_mfma_f32_16x16x32_f16(a0, bfr[nt], acc[0][nt], 0, 0, 0);
            acc[1][nt] = __builtin_amdgcn_mfma_f32_16x16x32_f16(a1, bfr[nt], acc[1][nt], 0, 0, 0);
        }
    }
    float b2v = b2[0];
#pragma unroll
    for (int mt = 0; mt < 2; mt++)
#pragma unroll
        for (int reg = 0; reg < 4; reg++) {
            float p = 0.0f;
#pragma unroll
            for (int nt = 0; nt < 4; nt++)
                p = fmaf(fmaxf(acc[mt][nt][reg], 0.0f), w2v[nt], p);
            p += __shfl_xor(p, 1);
            p += __shfl_xor(p, 2);
            p += __shfl_xor(p, 4);
            p += __shfl_xor(p, 8);
            if (col == 0) {
                int e = eb + wave * 32 + mt * 16 + quad * 4 + reg;
                if (e < E) out[e] = p + b2v;
            }
        }
}

extern "C" void kernel_launch(void* const* d_in, const int* in_sizes, int n_in,
                              void* d_out, int out_size, void* d_ws, size_t ws_size,
                              hipStream_t stream) {
    const float* x    = (const float*)d_in[0];
    const float* attr = (const float*)d_in[1];
    const float* W_e  = (const float*)d_in[2];
    const float* b_e  = (const float*)d_in[3];
    const float* W_c1 = (const float*)d_in[4];
    const float* b_c1 = (const float*)d_in[5];
    const float* W_c2 = (const float*)d_in[6];
    const float* b_c2 = (const float*)d_in[7];
    const float* W_p1 = (const float*)d_in[8];
    const float* b_p1 = (const float*)d_in[9];
    const float* W_p2 = (const float*)d_in[10];
    const float* b_p2 = (const float*)d_in[11];
    const void*  ei   = d_in[12];
    int N = in_sizes[0] / 32;
    int E = in_sizes[1] / 8;
    int n1 = N + 1;
    float* out = (float*)d_out;

    char* p = (char*)d_ws;
    auto alloc = [&](size_t bytes) { void* q = p; p += (bytes + 255) & ~(size_t)255; return q; };
    float* A            = (float*)alloc((size_t)N * 64 * 4);   // h0; hb aliases this later
    float* B            = (float*)alloc((size_t)N * 64 * 4);   // h1
    unsigned short* Hh  = (unsigned short*)alloc((size_t)N * 64 * 2);  // fp16 hW
    float* dinv         = (float*)alloc((size_t)N * 4);
    int* srcI           = (int*)alloc((size_t)E * 4);
    int* dstI           = (int*)alloc((size_t)E * 4);
    int* csr            = (int*)alloc((size_t)E * 4);
    int* deg            = (int*)alloc((size_t)n1 * 4);
    int* rowptr         = (int*)alloc((size_t)n1 * 4);
    int* part           = (int*)alloc((size_t)n1 * 4);
    int* bsum           = (int*)alloc(512 * 4);
    unsigned short* W1t = (unsigned short*)alloc(64 * 168 * 2);
    int* flag           = (int*)alloc(4);
    int* cursor = part;                      // part dead after scan_add
    unsigned short* hb = (unsigned short*)A; // h0 dead after lin2

    auto cdiv = [](long long a, long long b) { return (int)((a + b - 1) / b); };

    // indices -> int32
    detect_idx_k<<<1, 64, 0, stream>>>((const unsigned int*)ei, flag);
    cvt_idx_k<<<cdiv(2LL * E, 256), 256, 0, stream>>>(ei, flag, srcI, 2 * E);
    // CSR build
    hipMemsetAsync(deg, 0, (size_t)n1 * 4, stream);
    deg_i_k<<<cdiv(E, 256), 256, 0, stream>>>(dstI, deg, E);
    int nb = cdiv(n1, 256);
    scan_blk_k<<<nb, 256, 0, stream>>>(deg, part, bsum, n1);
    scan_tot_k<<<1, 512, 0, stream>>>(bsum, nb);
    scan_add_k<<<nb, 256, 0, stream>>>(part, bsum, rowptr, n1);
    dinv_k<<<cdiv(N, 256), 256, 0, stream>>>(deg, dinv, N);
    hipMemsetAsync(cursor, 0, (size_t)N * 4, stream);
    fill_csr_k<<<cdiv(E, 256), 256, 0, stream>>>(srcI, dstI, rowptr, cursor, csr, E);
    prep_w1_k<<<cdiv(64 * 168, 256), 256, 0, stream>>>(W_p1, W1t);
    // network
    int lg = cdiv(N, 128);
    lin_tile_k<32, true, true, false><<<lg, 256, 0, stream>>>(x, W_e, b_e, A, N);        // h0 -> A (f32)
    lin_tile_k<64, false, false, true><<<lg, 256, 0, stream>>>(A, W_c1, nullptr, Hh, N); // hW1 -> Hh (f16)
    conv_gather_k<false><<<cdiv(N, 4), 256, 0, stream>>>(Hh, dinv, rowptr, csr, b_c1, B, N);  // h1 -> B (f32)
    lin_tile_k<64, false, false, true><<<lg, 256, 0, stream>>>(B, W_c2, nullptr, Hh, N); // hW2 -> Hh (f16)
    conv_gather_k<true><<<cdiv(N, 4), 256, 0, stream>>>(Hh, dinv, rowptr, csr, b_c2, hb, N);  // h2 -> hb (f16)
    edge_mlp_mfma_k<<<cdiv(E, 128), 256, 0, stream>>>(hb, attr, srcI, dstI, W1t,
                                                      b_p1, W_p2, b_p2, out, E);
}

// Round 5
// 558.709 us; speedup vs baseline: 9.5393x; 1.1953x over previous
//
#include <hip/hip_runtime.h>
#include <hip/hip_fp16.h>

// ---------------------------------------------------------------------------
// GNN traffic predictor: embed -> GCNConv x2 -> edge MLP
// N=100000, E=1600000, F_NODE=32, F_EDGE=8, H=64
// Round 5: edge MLP with NO LDS -- W1 fragments persistent in registers
// (grid-stride wave loop), A-fragments gathered straight from global into
// MFMA layout (round-4 version was latency-bound at 2 blocks/CU: MfmaUtil 7%,
// VALUBusy 19%, occupancy 22%, 6e6 bank conflicts). conv_gather unroll 4->8.
// ---------------------------------------------------------------------------

typedef __attribute__((ext_vector_type(8))) _Float16 half8;
typedef __attribute__((ext_vector_type(4))) float f32x4;

__device__ __forceinline__ unsigned short f2h(float f) {
    return __half_as_ushort(__float2half(f));
}
__device__ __forceinline__ float h2f(unsigned short u) {
    return __half2float(__ushort_as_half(u));
}

// ---- index dtype detection: flag=1 -> int32, 0 -> int64 --------------------
__global__ void detect_idx_k(const unsigned int* __restrict__ ei, int* __restrict__ flag) {
    int nz = 0;
    for (int i = threadIdx.x; i < 2048; i += 64)
        if (ei[2 * i + 1] != 0u) nz = 1;
    unsigned long long m = __ballot(nz);
    if (threadIdx.x == 0) *flag = (m != 0ull) ? 1 : 0;
}

__global__ void cvt_idx_k(const void* __restrict__ ei, const int* __restrict__ flag,
                          int* __restrict__ out, int n) {
    int i = blockIdx.x * 256 + threadIdx.x;
    if (i >= n) return;
    if (*flag) out[i] = ((const int*)ei)[i];
    else       out[i] = (int)((const long long*)ei)[i];
}

// ---- CSR build -------------------------------------------------------------
__global__ void deg_i_k(const int* __restrict__ dst, int* __restrict__ deg, int E) {
    int i = blockIdx.x * 256 + threadIdx.x;
    if (i < E) atomicAdd(&deg[dst[i]], 1);
}

__global__ void scan_blk_k(const int* __restrict__ deg, int* __restrict__ part,
                           int* __restrict__ bsum, int n1) {
    __shared__ int s[256];
    int t = threadIdx.x;
    int i = blockIdx.x * 256 + t;
    int v = (i < n1) ? deg[i] : 0;
    s[t] = v;
    __syncthreads();
    for (int o = 1; o < 256; o <<= 1) {
        int x = (t >= o) ? s[t - o] : 0;
        __syncthreads();
        s[t] += x;
        __syncthreads();
    }
    if (i < n1) part[i] = s[t] - v;  // exclusive
    if (t == 255) bsum[blockIdx.x] = s[255];
}

__global__ void scan_tot_k(int* __restrict__ bsum, int nb) {
    __shared__ int s[512];
    int t = threadIdx.x;
    int v = (t < nb) ? bsum[t] : 0;
    s[t] = v;
    __syncthreads();
    for (int o = 1; o < 512; o <<= 1) {
        int x = (t >= o) ? s[t - o] : 0;
        __syncthreads();
        s[t] += x;
        __syncthreads();
    }
    if (t < nb) bsum[t] = s[t] - v;  // exclusive block offsets
}

__global__ void scan_add_k(const int* __restrict__ part, const int* __restrict__ bsum,
                           int* __restrict__ rowptr, int n1) {
    int i = blockIdx.x * 256 + threadIdx.x;
    if (i < n1) rowptr[i] = part[i] + bsum[blockIdx.x];
}

__global__ void dinv_k(const int* __restrict__ deg, float* __restrict__ dinv, int n) {
    int i = blockIdx.x * 256 + threadIdx.x;
    if (i < n) dinv[i] = rsqrtf((float)deg[i] + 1.0f);  // +1 self-loop
}

__global__ void fill_csr_k(const int* __restrict__ src, const int* __restrict__ dst,
                           const int* __restrict__ rowptr, int* __restrict__ cursor,
                           int* __restrict__ csr, int E) {
    int e = blockIdx.x * 256 + threadIdx.x;
    if (e >= E) return;
    int d = dst[e];
    int pos = rowptr[d] + atomicAdd(&cursor[d], 1);
    csr[pos] = src[e];
}

// ---- W1 -> fp16 transposed, padded [64][168], zero K-tail ------------------
// Zero tail k in [136,168) makes A-fragment garbage in k [136,160) harmless.
__global__ void prep_w1_k(const float* __restrict__ W1, unsigned short* __restrict__ W1t) {
    int i = blockIdx.x * 256 + threadIdx.x;
    if (i >= 64 * 168) return;
    int n = i / 168, k = i % 168;
    float v = (k < 136) ? W1[k * 64 + n] : 0.0f;
    W1t[i] = f2h(v);
}

// ---- register-tiled GEMM: C[n,64] = act(A[n,K] @ W[K,64] (+b)) -------------
// launch_bounds(256,4): cap 128 VGPRs (round-3 had 256 + spills).
template <int K, bool BIAS, bool RELU, bool F16OUT>
__global__ __launch_bounds__(256, 4) void lin_tile_k(
    const float* __restrict__ A, const float* __restrict__ W,
    const float* __restrict__ b, void* __restrict__ outv, int n) {
    constexpr int KP = K + 4;
    __shared__ float As[128 * KP];
    __shared__ float Ws[64 * KP];
    int t = threadIdx.x;
    constexpr int K4 = K / 4;
    for (int i = t; i < 128 * K4; i += 256) {
        int r = i / K4, c4 = i % K4;
        int row = blockIdx.x * 128 + r;
        row = row < n ? row : n - 1;
        *(float4*)&As[r * KP + c4 * 4] = *(const float4*)&A[(size_t)row * K + c4 * 4];
    }
    for (int i = t; i < K * 64; i += 256) {
        int k = i >> 6, j = i & 63;
        Ws[j * KP + k] = W[i];
    }
    __syncthreads();
    int lane = t & 63;
    int wave = t >> 6;
    int ri = lane >> 3, ji = lane & 7;
    float acc[4][8];
#pragma unroll
    for (int m = 0; m < 4; m++)
#pragma unroll
        for (int c = 0; c < 8; c++) acc[m][c] = BIAS ? b[ji + 8 * c] : 0.0f;
#pragma unroll 2
    for (int kc = 0; kc < K; kc += 4) {
        float4 a[4], w[8];
#pragma unroll
        for (int m = 0; m < 4; m++)
            a[m] = *(const float4*)&As[(wave * 32 + ri + 8 * m) * KP + kc];
#pragma unroll
        for (int c = 0; c < 8; c++)
            w[c] = *(const float4*)&Ws[(ji + 8 * c) * KP + kc];
#pragma unroll
        for (int m = 0; m < 4; m++)
#pragma unroll
            for (int c = 0; c < 8; c++) {
                acc[m][c] = fmaf(a[m].x, w[c].x, acc[m][c]);
                acc[m][c] = fmaf(a[m].y, w[c].y, acc[m][c]);
                acc[m][c] = fmaf(a[m].z, w[c].z, acc[m][c]);
                acc[m][c] = fmaf(a[m].w, w[c].w, acc[m][c]);
            }
    }
#pragma unroll
    for (int m = 0; m < 4; m++) {
        int row = blockIdx.x * 128 + wave * 32 + ri + 8 * m;
        if (row < n) {
#pragma unroll
            for (int c = 0; c < 8; c++) {
                float v = acc[m][c];
                if (RELU) v = fmaxf(v, 0.0f);
                if (F16OUT) ((unsigned short*)outv)[(size_t)row * 64 + ji + 8 * c] = f2h(v);
                else        ((float*)outv)[(size_t)row * 64 + ji + 8 * c] = v;
            }
        }
    }
}

// ---- conv gather: out[d] = relu((sum_{e->d} hW[s]*dinv[s] + hW[d]*dv)*dv + b)
// hW in fp16; fp32 accumulation; 8-wide unroll for outstanding row reads.
template <bool F16OUT>
__global__ __launch_bounds__(256) void conv_gather_k(
    const unsigned short* __restrict__ hW, const float* __restrict__ dinv,
    const int* __restrict__ rowptr, const int* __restrict__ csr,
    const float* __restrict__ b, void* __restrict__ outv, int n) {
    int lane = threadIdx.x & 63;
    int wave = threadIdx.x >> 6;
    int node = blockIdx.x * 4 + wave;
    if (node >= n) return;
    int beg = rowptr[node], end = rowptr[node + 1];
    float dv = dinv[node];
    float acc = h2f(hW[(size_t)node * 64 + lane]) * dv;  // self-loop
    int i = beg;
    for (; i + 8 <= end; i += 8) {
        int s[8];
#pragma unroll
        for (int u = 0; u < 8; u++) s[u] = csr[i + u];
        float h[8], w[8];
#pragma unroll
        for (int u = 0; u < 8; u++) h[u] = h2f(hW[(size_t)s[u] * 64 + lane]);
#pragma unroll
        for (int u = 0; u < 8; u++) w[u] = dinv[s[u]];
#pragma unroll
        for (int u = 0; u < 8; u++) acc = fmaf(h[u], w[u], acc);
    }
    for (; i + 4 <= end; i += 4) {
        int s0 = csr[i], s1 = csr[i + 1], s2 = csr[i + 2], s3 = csr[i + 3];
        float h0 = h2f(hW[(size_t)s0 * 64 + lane]);
        float h1 = h2f(hW[(size_t)s1 * 64 + lane]);
        float h2 = h2f(hW[(size_t)s2 * 64 + lane]);
        float h3 = h2f(hW[(size_t)s3 * 64 + lane]);
        acc = fmaf(h0, dinv[s0], acc);
        acc = fmaf(h1, dinv[s1], acc);
        acc = fmaf(h2, dinv[s2], acc);
        acc = fmaf(h3, dinv[s3], acc);
    }
    for (; i < end; i++) {
        int s = csr[i];
        acc = fmaf(h2f(hW[(size_t)s * 64 + lane]), dinv[s], acc);
    }
    float v = fmaxf(fmaf(acc, dv, b[lane]), 0.0f);
    if (F16OUT) ((unsigned short*)outv)[(size_t)node * 64 + lane] = f2h(v);
    else        ((float*)outv)[(size_t)node * 64 + lane] = v;
}

// ---- edge MLP via MFMA, direct global->register gather, no LDS -------------
// out[e] = relu([h[s],h[d],attr] @ W1 + b1) . W2 + b2; h fp16, W1 fp16.
// Wave-independent: W1 frags (4 N-tiles x 5 K-chunks = 80 VGPR) loaded once,
// grid-stride loop over 32-edge groups. A-frag (m=lane&15, k=quad*8+j) for
// 16x16x32 is 16 contiguous bytes of hb[src]/hb[dst]/attr -> gather = frag.
// K-chunk 4 (k 128..159): quad 0 = attr, quads 1-3 garbage x W1t-zero-tail = 0.
__global__ __launch_bounds__(256, 3) void edge_mlp_direct_k(
    const unsigned short* __restrict__ hb, const float* __restrict__ attr,
    const int* __restrict__ src, const int* __restrict__ dst,
    const unsigned short* __restrict__ W1t,  // [64][168] fp16, transposed+padded
    const float* __restrict__ b1, const float* __restrict__ W2,
    const float* __restrict__ b2, float* __restrict__ out, int E, int nwaves) {
    int t = threadIdx.x;
    int lane = t & 63;
    int col = lane & 15;
    int quad = lane >> 4;
    int wid = blockIdx.x * 4 + (t >> 6);

    // persistent W1 fragments: Wf[nt][kc] = B[k=kc*32+quad*8+j][n=nt*16+col]
    half8 Wf[4][5];
#pragma unroll
    for (int nt = 0; nt < 4; nt++)
#pragma unroll
        for (int kc = 0; kc < 5; kc++)
            Wf[nt][kc] = *(const half8*)&W1t[(nt * 16 + col) * 168 + kc * 32 + quad * 8];
    float b1v[4], w2v[4];
#pragma unroll
    for (int nt = 0; nt < 4; nt++) {
        b1v[nt] = b1[nt * 16 + col];
        w2v[nt] = W2[nt * 16 + col];
    }
    float b2v = b2[0];

    for (int base = wid * 32; base < E; base += nwaves * 32) {
        f32x4 acc[2][4];
#pragma unroll
        for (int mt = 0; mt < 2; mt++)
#pragma unroll
            for (int nt = 0; nt < 4; nt++)
                acc[mt][nt] = (f32x4){b1v[nt], b1v[nt], b1v[nt], b1v[nt]};
#pragma unroll
        for (int mt = 0; mt < 2; mt++) {
            int e = base + mt * 16 + col;
            e = e < E ? e : E - 1;
            int s = src[e], d = dst[e];
            half8 a0 = *(const half8*)&hb[(size_t)s * 64 + quad * 8];
            half8 a1 = *(const half8*)&hb[(size_t)s * 64 + 32 + quad * 8];
            half8 a2 = *(const half8*)&hb[(size_t)d * 64 + quad * 8];
            half8 a3 = *(const half8*)&hb[(size_t)d * 64 + 32 + quad * 8];
            half8 a4;
            if (quad == 0) {
                float4 x0 = ((const float4*)attr)[(size_t)e * 2];
                float4 x1 = ((const float4*)attr)[(size_t)e * 2 + 1];
                a4[0] = (_Float16)x0.x; a4[1] = (_Float16)x0.y;
                a4[2] = (_Float16)x0.z; a4[3] = (_Float16)x0.w;
                a4[4] = (_Float16)x1.x; a4[5] = (_Float16)x1.y;
                a4[6] = (_Float16)x1.z; a4[7] = (_Float16)x1.w;
            } else {
                a4 = (half8)(_Float16)0.0f;  // k>=136 would be garbage x 0 anyway
            }
#pragma unroll
            for (int nt = 0; nt < 4; nt++) {
                acc[mt][nt] = __builtin_amdgcn_mfma_f32_16x16x32_f16(a0, Wf[nt][0], acc[mt][nt], 0, 0, 0);
                acc[mt][nt] = __builtin_amdgcn_mfma_f32_16x16x32_f16(a1, Wf[nt][1], acc[mt][nt], 0, 0, 0);
                acc[mt][nt] = __builtin_amdgcn_mfma_f32_16x16x32_f16(a2, Wf[nt][2], acc[mt][nt], 0, 0, 0);
                acc[mt][nt] = __builtin_amdgcn_mfma_f32_16x16x32_f16(a3, Wf[nt][3], acc[mt][nt], 0, 0, 0);
                acc[mt][nt] = __builtin_amdgcn_mfma_f32_16x16x32_f16(a4, Wf[nt][4], acc[mt][nt], 0, 0, 0);
            }
        }
        // layer 2: relu(z).W2 + b2; C/D: col=lane&15 (feature), row=quad*4+reg (edge)
#pragma unroll
        for (int mt = 0; mt < 2; mt++)
#pragma unroll
            for (int reg = 0; reg < 4; reg++) {
                float p = 0.0f;
#pragma unroll
                for (int nt = 0; nt < 4; nt++)
                    p = fmaf(fmaxf(acc[mt][nt][reg], 0.0f), w2v[nt], p);
                p += __shfl_xor(p, 1);
                p += __shfl_xor(p, 2);
                p += __shfl_xor(p, 4);
                p += __shfl_xor(p, 8);
                if (col == 0) {
                    int e = base + mt * 16 + quad * 4 + reg;
                    if (e < E) out[e] = p + b2v;
                }
            }
    }
}

extern "C" void kernel_launch(void* const* d_in, const int* in_sizes, int n_in,
                              void* d_out, int out_size, void* d_ws, size_t ws_size,
                              hipStream_t stream) {
    const float* x    = (const float*)d_in[0];
    const float* attr = (const float*)d_in[1];
    const float* W_e  = (const float*)d_in[2];
    const float* b_e  = (const float*)d_in[3];
    const float* W_c1 = (const float*)d_in[4];
    const float* b_c1 = (const float*)d_in[5];
    const float* W_c2 = (const float*)d_in[6];
    const float* b_c2 = (const float*)d_in[7];
    const float* W_p1 = (const float*)d_in[8];
    const float* b_p1 = (const float*)d_in[9];
    const float* W_p2 = (const float*)d_in[10];
    const float* b_p2 = (const float*)d_in[11];
    const void*  ei   = d_in[12];
    int N = in_sizes[0] / 32;
    int E = in_sizes[1] / 8;
    int n1 = N + 1;
    float* out = (float*)d_out;

    char* p = (char*)d_ws;
    auto alloc = [&](size_t bytes) { void* q = p; p += (bytes + 255) & ~(size_t)255; return q; };
    float* A            = (float*)alloc((size_t)N * 64 * 4);   // h0; hb aliases this later
    float* B            = (float*)alloc((size_t)N * 64 * 4);   // h1
    unsigned short* Hh  = (unsigned short*)alloc((size_t)N * 64 * 2);  // fp16 hW
    float* dinv         = (float*)alloc((size_t)N * 4);
    int* srcI           = (int*)alloc((size_t)E * 4);
    int* dstI           = (int*)alloc((size_t)E * 4);
    int* csr            = (int*)alloc((size_t)E * 4);
    int* deg            = (int*)alloc((size_t)n1 * 4);
    int* rowptr         = (int*)alloc((size_t)n1 * 4);
    int* part           = (int*)alloc((size_t)n1 * 4);
    int* bsum           = (int*)alloc(512 * 4);
    unsigned short* W1t = (unsigned short*)alloc(64 * 168 * 2);
    int* flag           = (int*)alloc(4);
    int* cursor = part;                      // part dead after scan_add
    unsigned short* hb = (unsigned short*)A; // h0 dead after lin2

    auto cdiv = [](long long a, long long b) { return (int)((a + b - 1) / b); };

    // indices -> int32
    detect_idx_k<<<1, 64, 0, stream>>>((const unsigned int*)ei, flag);
    cvt_idx_k<<<cdiv(2LL * E, 256), 256, 0, stream>>>(ei, flag, srcI, 2 * E);
    // CSR build
    hipMemsetAsync(deg, 0, (size_t)n1 * 4, stream);
    deg_i_k<<<cdiv(E, 256), 256, 0, stream>>>(dstI, deg, E);
    int nb = cdiv(n1, 256);
    scan_blk_k<<<nb, 256, 0, stream>>>(deg, part, bsum, n1);
    scan_tot_k<<<1, 512, 0, stream>>>(bsum, nb);
    scan_add_k<<<nb, 256, 0, stream>>>(part, bsum, rowptr, n1);
    dinv_k<<<cdiv(N, 256), 256, 0, stream>>>(deg, dinv, N);
    hipMemsetAsync(cursor, 0, (size_t)N * 4, stream);
    fill_csr_k<<<cdiv(E, 256), 256, 0, stream>>>(srcI, dstI, rowptr, cursor, csr, E);
    prep_w1_k<<<cdiv(64 * 168, 256), 256, 0, stream>>>(W_p1, W1t);
    // network
    int lg = cdiv(N, 128);
    lin_tile_k<32, true, true, false><<<lg, 256, 0, stream>>>(x, W_e, b_e, A, N);        // h0 -> A (f32)
    lin_tile_k<64, false, false, true><<<lg, 256, 0, stream>>>(A, W_c1, nullptr, Hh, N); // hW1 -> Hh (f16)
    conv_gather_k<false><<<cdiv(N, 4), 256, 0, stream>>>(Hh, dinv, rowptr, csr, b_c1, B, N);  // h1 -> B (f32)
    lin_tile_k<64, false, false, true><<<lg, 256, 0, stream>>>(B, W_c2, nullptr, Hh, N); // hW2 -> Hh (f16)
    conv_gather_k<true><<<cdiv(N, 4), 256, 0, stream>>>(Hh, dinv, rowptr, csr, b_c2, hb, N);  // h2 -> hb (f16)
    const int NB = 768;  // 3072 waves, grid-stride over 32-edge groups
    edge_mlp_direct_k<<<NB, 256, 0, stream>>>(hb, attr, srcI, dstI, W1t,
                                              b_p1, W_p2, b_p2, out, E, NB * 4);
}